// Round 1
// baseline (1706.866 us; speedup 1.0000x reference)
//
#include <hip/hip_runtime.h>
#include <hip/hip_bf16.h>
#include <math.h>

// Problem dims (fixed by the reference):
//   B=8, P_LEN=2048, Q_LEN=1024, HID=1024
// Pipeline:
//   1. p_key = relu(k @ Wk^T)            [B*P, H]   (gemm_nt, batch=1)
//   2. q_key = relu(q @ Wq^T)            [B*Q, H]   (gemm_nt, batch=1)
//   3. scores = p_key @ q_key^T          [B, P, Q]  (gemm_nt batched) -> written into alphas slice of d_out
//   4. softmax rows (mask -> -inf)       in place
//   5. ctx = alphas @ q                  [B, P, H]  (gemm_nn batched) -> d_out base

#define BM 64
#define BN 64
#define BK 16
#define LDP 68   // padded LDS stride (mult of 4 keeps float4 alignment, breaks bank stride)

// C[m,n] = (relu?) sum_k A[m,k]*B[n,k]   -- both operands K-major ("NT")
__global__ __launch_bounds__(256) void gemm_nt_kernel(
    const float* __restrict__ A, const float* __restrict__ B,
    float* __restrict__ C, int M, int N, int K,
    long long sA, long long sB, long long sC, int relu)
{
  __shared__ float As[BK][LDP];
  __shared__ float Bs[BK][LDP];
  const int bz = blockIdx.z;
  A += (long long)bz * sA;
  B += (long long)bz * sB;
  C += (long long)bz * sC;
  const int m0 = blockIdx.y * BM;
  const int n0 = blockIdx.x * BN;
  const int t  = threadIdx.x;
  const int tx = t & 15, ty = t >> 4;
  const int lr = t >> 2;          // 0..63 : tile row
  const int lk = (t & 3) << 2;    // 0,4,8,12 : k offset
  float acc[4][4] = {{0.f, 0.f, 0.f, 0.f}};
  const float* Ap = A + (long long)(m0 + lr) * K + lk;
  const float* Bp = B + (long long)(n0 + lr) * K + lk;
  for (int k0 = 0; k0 < K; k0 += BK) {
    float4 av = *(const float4*)(Ap + k0);
    float4 bv = *(const float4*)(Bp + k0);
    __syncthreads();
    As[lk + 0][lr] = av.x; As[lk + 1][lr] = av.y;
    As[lk + 2][lr] = av.z; As[lk + 3][lr] = av.w;
    Bs[lk + 0][lr] = bv.x; Bs[lk + 1][lr] = bv.y;
    Bs[lk + 2][lr] = bv.z; Bs[lk + 3][lr] = bv.w;
    __syncthreads();
#pragma unroll
    for (int kk = 0; kk < BK; ++kk) {
      float4 a4 = *(const float4*)&As[kk][ty << 2];
      float4 b4 = *(const float4*)&Bs[kk][tx << 2];
      const float ar[4] = {a4.x, a4.y, a4.z, a4.w};
      const float br[4] = {b4.x, b4.y, b4.z, b4.w};
#pragma unroll
      for (int i = 0; i < 4; ++i)
#pragma unroll
        for (int j = 0; j < 4; ++j)
          acc[i][j] = fmaf(ar[i], br[j], acc[i][j]);
    }
  }
#pragma unroll
  for (int i = 0; i < 4; ++i) {
    float4 o;
    o.x = acc[i][0]; o.y = acc[i][1]; o.z = acc[i][2]; o.w = acc[i][3];
    if (relu) {
      o.x = fmaxf(o.x, 0.f); o.y = fmaxf(o.y, 0.f);
      o.z = fmaxf(o.z, 0.f); o.w = fmaxf(o.w, 0.f);
    }
    *(float4*)(C + (long long)(m0 + (ty << 2) + i) * N + n0 + (tx << 2)) = o;
  }
}

// C[m,n] = sum_k A[m,k]*B[k,n]   -- B is K x N row-major ("NN")
__global__ __launch_bounds__(256) void gemm_nn_kernel(
    const float* __restrict__ A, const float* __restrict__ B,
    float* __restrict__ C, int M, int N, int K,
    long long sA, long long sB, long long sC)
{
  __shared__ float As[BK][LDP];
  __shared__ float Bs[BK][LDP];
  const int bz = blockIdx.z;
  A += (long long)bz * sA;
  B += (long long)bz * sB;
  C += (long long)bz * sC;
  const int m0 = blockIdx.y * BM;
  const int n0 = blockIdx.x * BN;
  const int t  = threadIdx.x;
  const int tx = t & 15, ty = t >> 4;
  const int lr = t >> 2;          // A tile row
  const int lk = (t & 3) << 2;    // A tile k offset
  const int bk = t >> 4;          // B tile k row (0..15)
  const int bn = (t & 15) << 2;   // B tile n offset
  float acc[4][4] = {{0.f, 0.f, 0.f, 0.f}};
  const float* Ap = A + (long long)(m0 + lr) * K + lk;
  for (int k0 = 0; k0 < K; k0 += BK) {
    float4 av = *(const float4*)(Ap + k0);
    float4 bv = *(const float4*)(B + (long long)(k0 + bk) * N + n0 + bn);
    __syncthreads();
    As[lk + 0][lr] = av.x; As[lk + 1][lr] = av.y;
    As[lk + 2][lr] = av.z; As[lk + 3][lr] = av.w;
    *(float4*)&Bs[bk][bn] = bv;
    __syncthreads();
#pragma unroll
    for (int kk = 0; kk < BK; ++kk) {
      float4 a4 = *(const float4*)&As[kk][ty << 2];
      float4 b4 = *(const float4*)&Bs[kk][tx << 2];
      const float ar[4] = {a4.x, a4.y, a4.z, a4.w};
      const float br[4] = {b4.x, b4.y, b4.z, b4.w};
#pragma unroll
      for (int i = 0; i < 4; ++i)
#pragma unroll
        for (int j = 0; j < 4; ++j)
          acc[i][j] = fmaf(ar[i], br[j], acc[i][j]);
    }
  }
#pragma unroll
  for (int i = 0; i < 4; ++i) {
    float4 o;
    o.x = acc[i][0]; o.y = acc[i][1]; o.z = acc[i][2]; o.w = acc[i][3];
    *(float4*)(C + (long long)(m0 + (ty << 2) + i) * N + n0 + (tx << 2)) = o;
  }
}

// One block per (b,p) row; row length Q=1024, 256 threads * 4 floats.
__global__ __launch_bounds__(256) void softmax_rows_kernel(
    float* __restrict__ S, const unsigned char* __restrict__ qmask,
    int Q, int P)
{
  const long long row = blockIdx.x;       // b*P + p
  const int b = (int)(row / P);
  float* s = S + row * (long long)Q;
  const unsigned char* msk = qmask + (long long)b * Q;
  const int t = threadIdx.x;
  float4 v = *(const float4*)(s + (t << 2));
  float vals[4] = {v.x, v.y, v.z, v.w};
#pragma unroll
  for (int j = 0; j < 4; ++j)
    if (msk[(t << 2) + j]) vals[j] = -INFINITY;

  __shared__ float red[8];
  const int wid = t >> 6, lid = t & 63;

  float mx = fmaxf(fmaxf(vals[0], vals[1]), fmaxf(vals[2], vals[3]));
#pragma unroll
  for (int o = 32; o > 0; o >>= 1) mx = fmaxf(mx, __shfl_xor(mx, o, 64));
  if (lid == 0) red[wid] = mx;
  __syncthreads();
  mx = fmaxf(fmaxf(red[0], red[1]), fmaxf(red[2], red[3]));

  float e[4];
  float sum = 0.f;
#pragma unroll
  for (int j = 0; j < 4; ++j) { e[j] = __expf(vals[j] - mx); sum += e[j]; }
#pragma unroll
  for (int o = 32; o > 0; o >>= 1) sum += __shfl_xor(sum, o, 64);
  __syncthreads();
  if (lid == 0) red[4 + wid] = sum;
  __syncthreads();
  sum = red[4] + red[5] + red[6] + red[7];
  const float inv = 1.f / sum;

  float4 o;
  o.x = e[0] * inv; o.y = e[1] * inv; o.z = e[2] * inv; o.w = e[3] * inv;
  *(float4*)(s + (t << 2)) = o;
}

extern "C" void kernel_launch(void* const* d_in, const int* in_sizes, int n_in,
                              void* d_out, int out_size, void* d_ws, size_t ws_size,
                              hipStream_t stream)
{
  const int B = 8, P = 2048, Q = 1024, H = 1024;
  const float* k  = (const float*)d_in[0];
  const float* q  = (const float*)d_in[1];
  const unsigned char* qmask = (const unsigned char*)d_in[2];  // jax bool -> 1 byte each
  const float* Wk = (const float*)d_in[3];
  const float* Wq = (const float*)d_in[4];

  float* ctx    = (float*)d_out;                  // [B,P,H]
  float* alphas = ctx + (size_t)B * P * H;        // [B,P,Q]

  // workspace: p_key (64 MB) + q_key (32 MB)
  float* pkey = (float*)d_ws;                     // [B*P, H]
  float* qkey = pkey + (size_t)B * P * H;         // [B*Q, H]

  // 1. p_key = relu(k @ Wk^T)
  gemm_nt_kernel<<<dim3(H / BN, (B * P) / BM, 1), 256, 0, stream>>>(
      k, Wk, pkey, B * P, H, H, 0LL, 0LL, 0LL, 1);
  // 2. q_key = relu(q @ Wq^T)
  gemm_nt_kernel<<<dim3(H / BN, (B * Q) / BM, 1), 256, 0, stream>>>(
      q, Wq, qkey, B * Q, H, H, 0LL, 0LL, 0LL, 1);
  // 3. scores = p_key @ q_key^T  (batched) -> alphas slice of d_out
  gemm_nt_kernel<<<dim3(Q / BN, P / BM, B), 256, 0, stream>>>(
      pkey, qkey, alphas, P, Q, H,
      (long long)P * H, (long long)Q * H, (long long)P * Q, 0);
  // 4. softmax in place (with q_mask)
  softmax_rows_kernel<<<B * P, 256, 0, stream>>>(alphas, qmask, Q, P);
  // 5. ctx = alphas @ q  (batched NN)
  gemm_nn_kernel<<<dim3(H / BN, P / BM, B), 256, 0, stream>>>(
      alphas, q, ctx, P, H, Q,
      (long long)P * Q, (long long)Q * H, (long long)P * H);
}

// Round 2
// 467.874 us; speedup vs baseline: 3.6481x; 3.6481x over previous
//
#include <hip/hip_runtime.h>
#include <hip/hip_bf16.h>
#include <math.h>

// B=8, P=2048, Q=1024, H=1024
// 1. convert k,q,Wk,Wq fp32 -> fp16
// 2. pkey16 = relu(k @ Wk^T)   MFMA f16, fp16 out (stored in d_out ctx region, dead until step 7)
// 3. qkey16 = relu(q @ Wq^T)   MFMA f16, fp16 out
// 4. scores = pkey @ qkey^T    MFMA f16, fp32 out -> alphas slice of d_out
// 5. qT16 = transpose(q) fp16  (aliases q16, dead after step 3)
// 6. softmax rows in place, also emit fp16 alphas (aliases k16, dead after step 2)
// 7. ctx = alphas16 @ qT16^T   MFMA f16, fp32 out -> d_out base (overwrites pkey16)

typedef _Float16 v8h __attribute__((ext_vector_type(8)));
typedef _Float16 v4h __attribute__((ext_vector_type(4)));
typedef float v4f __attribute__((ext_vector_type(4)));

#define AS1C(p) ((const __attribute__((address_space(1))) void*)(p))
#define AS3(p)  ((__attribute__((address_space(3))) void*)(p))

// ---------------------------------------------------------------------------
// NT MFMA GEMM: C[m,n] = sum_k A[m,k] * B[n,k], A:[M,K] B:[N,K] row-major f16.
// 128x128 tile, BK=32, 256 threads (4 waves, 2x2 wave grid, 64x64 per wave).
// Cf (fp32) and/or Ch (fp16) outputs; optional relu.
__global__ __launch_bounds__(256) void gemm_nt_f16(
    const _Float16* __restrict__ A, const _Float16* __restrict__ B,
    float* __restrict__ Cf, _Float16* __restrict__ Ch,
    int M, int N, int K,
    long long sA, long long sB, long long sC, int relu)
{
  __shared__ _Float16 As[128 * 32];
  __shared__ _Float16 Bs[128 * 32];

  const int bz = blockIdx.z;
  A += (long long)bz * sA;
  B += (long long)bz * sB;

  const int m0 = blockIdx.y * 128;
  const int n0 = blockIdx.x * 128;
  const int t  = threadIdx.x;
  const int l  = t & 63;
  const int w  = t >> 6;
  const int wm = (w >> 1) * 64;   // wave m offset in tile
  const int wn = (w & 1) * 64;    // wave n offset in tile
  const int fr = l & 15;          // fragment row/col index
  const int fq = l >> 4;          // quad

  // staging decomposition: chunk c in {0,1}: lin = c*256 + t
  // row = lin>>2 (0..127), col = (lin&3)*8
  const int srow = t >> 2;
  const int scol = (t & 3) << 3;

  v4f acc[4][4];
#pragma unroll
  for (int i = 0; i < 4; ++i)
#pragma unroll
    for (int j = 0; j < 4; ++j)
      acc[i][j] = (v4f){0.f, 0.f, 0.f, 0.f};

  const _Float16* Ap = A + (long long)(m0 + srow) * K + scol;
  const _Float16* Bp = B + (long long)(n0 + srow) * K + scol;

  for (int k0 = 0; k0 < K; k0 += 32) {
    // stage A,B tiles: 128 rows x 32 halfs = 8 KB each; 16B per lane per call
    __builtin_amdgcn_global_load_lds(AS1C(Ap + k0),        AS3(As + t * 8),         16, 0, 0);
    __builtin_amdgcn_global_load_lds(AS1C(Ap + 64 * K + k0), AS3(As + 2048 + t * 8), 16, 0, 0);
    __builtin_amdgcn_global_load_lds(AS1C(Bp + k0),        AS3(Bs + t * 8),         16, 0, 0);
    __builtin_amdgcn_global_load_lds(AS1C(Bp + 64 * K + k0), AS3(Bs + 2048 + t * 8), 16, 0, 0);
    __syncthreads();

    v8h a[4], b[4];
#pragma unroll
    for (int i = 0; i < 4; ++i)
      a[i] = *(const v8h*)&As[(wm + i * 16 + fr) * 32 + fq * 8];
#pragma unroll
    for (int j = 0; j < 4; ++j)
      b[j] = *(const v8h*)&Bs[(wn + j * 16 + fr) * 32 + fq * 8];

#pragma unroll
    for (int i = 0; i < 4; ++i)
#pragma unroll
      for (int j = 0; j < 4; ++j)
        acc[i][j] = __builtin_amdgcn_mfma_f32_16x16x32_f16(a[i], b[j], acc[i][j], 0, 0, 0);

    __syncthreads();
  }

  // epilogue: C/D layout col = lane&15, row = (lane>>4)*4 + reg
  float* Cfb = Cf ? Cf + (long long)bz * sC : nullptr;
  _Float16* Chb = Ch ? Ch + (long long)bz * sC : nullptr;
#pragma unroll
  for (int i = 0; i < 4; ++i) {
#pragma unroll
    for (int j = 0; j < 4; ++j) {
#pragma unroll
      for (int r = 0; r < 4; ++r) {
        const int row = m0 + wm + i * 16 + fq * 4 + r;
        const int col = n0 + wn + j * 16 + fr;
        float v = acc[i][j][r];
        if (relu) v = fmaxf(v, 0.f);
        if (Cfb) Cfb[(long long)row * N + col] = v;
        if (Chb) Chb[(long long)row * N + col] = (_Float16)v;
      }
    }
  }
}

// ---------------------------------------------------------------------------
__global__ __launch_bounds__(256) void f32_to_f16_kernel(
    const float* __restrict__ in, _Float16* __restrict__ out, long long n)
{
  const long long i = ((long long)blockIdx.x * 256 + threadIdx.x) * 4;
  if (i >= n) return;
  const float4 v = *(const float4*)(in + i);
  v4h o = {(_Float16)v.x, (_Float16)v.y, (_Float16)v.z, (_Float16)v.w};
  *(v4h*)(out + i) = o;
}

// q [B,Q,H] fp32 -> qT [B,H,Q] fp16, 64x64 tiles
__global__ __launch_bounds__(256) void transpose_f16_kernel(
    const float* __restrict__ q, _Float16* __restrict__ qT, int Q, int H)
{
  __shared__ float tile[64][65];
  const float* qb = q + (long long)blockIdx.z * Q * H;
  _Float16* qTb = qT + (long long)blockIdx.z * H * Q;
  const int q0 = blockIdx.x * 64, h0 = blockIdx.y * 64;
  const int t = threadIdx.x;
  const int tr = t >> 4, tc = (t & 15) << 2;
#pragma unroll
  for (int i = 0; i < 4; ++i) {
    const float4 v = *(const float4*)(qb + (long long)(q0 + tr + i * 16) * H + h0 + tc);
    tile[tr + i * 16][tc + 0] = v.x;
    tile[tr + i * 16][tc + 1] = v.y;
    tile[tr + i * 16][tc + 2] = v.z;
    tile[tr + i * 16][tc + 3] = v.w;
  }
  __syncthreads();
#pragma unroll
  for (int i = 0; i < 4; ++i) {
    const int hl = tr + i * 16;
    const int ql = tc;
    v4h o = {(_Float16)tile[ql + 0][hl], (_Float16)tile[ql + 1][hl],
             (_Float16)tile[ql + 2][hl], (_Float16)tile[ql + 3][hl]};
    *(v4h*)(qTb + (long long)(h0 + hl) * Q + q0 + ql) = o;
  }
}

// softmax rows of S [B*P, Q] fp32 in place; also write fp16 copy
__global__ __launch_bounds__(256) void softmax_rows_kernel(
    float* __restrict__ S, _Float16* __restrict__ S16,
    const unsigned char* __restrict__ qmask, int Q, int P)
{
  const long long row = blockIdx.x;       // b*P + p
  const int b = (int)(row / P);
  float* s = S + row * (long long)Q;
  const unsigned char* msk = qmask + (long long)b * Q;
  const int t = threadIdx.x;
  float4 v = *(const float4*)(s + (t << 2));
  float vals[4] = {v.x, v.y, v.z, v.w};
#pragma unroll
  for (int j = 0; j < 4; ++j)
    if (msk[(t << 2) + j]) vals[j] = -INFINITY;

  __shared__ float red[8];
  const int wid = t >> 6, lid = t & 63;

  float mx = fmaxf(fmaxf(vals[0], vals[1]), fmaxf(vals[2], vals[3]));
#pragma unroll
  for (int o = 32; o > 0; o >>= 1) mx = fmaxf(mx, __shfl_xor(mx, o, 64));
  if (lid == 0) red[wid] = mx;
  __syncthreads();
  mx = fmaxf(fmaxf(red[0], red[1]), fmaxf(red[2], red[3]));

  float e[4];
  float sum = 0.f;
#pragma unroll
  for (int j = 0; j < 4; ++j) { e[j] = __expf(vals[j] - mx); sum += e[j]; }
#pragma unroll
  for (int o = 32; o > 0; o >>= 1) sum += __shfl_xor(sum, o, 64);
  __syncthreads();
  if (lid == 0) red[4 + wid] = sum;
  __syncthreads();
  sum = red[4] + red[5] + red[6] + red[7];
  const float inv = 1.f / sum;

  float4 o;
  o.x = e[0] * inv; o.y = e[1] * inv; o.z = e[2] * inv; o.w = e[3] * inv;
  *(float4*)(s + (t << 2)) = o;
  v4h oh = {(_Float16)o.x, (_Float16)o.y, (_Float16)o.z, (_Float16)o.w};
  *(v4h*)(S16 + row * (long long)Q + (t << 2)) = oh;
}

// ---------------------------------------------------------------------------
extern "C" void kernel_launch(void* const* d_in, const int* in_sizes, int n_in,
                              void* d_out, int out_size, void* d_ws, size_t ws_size,
                              hipStream_t stream)
{
  const int B = 8, P = 2048, Q = 1024, H = 1024;
  const float* k  = (const float*)d_in[0];
  const float* q  = (const float*)d_in[1];
  const unsigned char* qmask = (const unsigned char*)d_in[2];
  const float* Wk = (const float*)d_in[3];
  const float* Wq = (const float*)d_in[4];

  float* ctx    = (float*)d_out;                  // [B,P,H] fp32
  float* alphas = ctx + (size_t)B * P * H;        // [B,P,Q] fp32

  // pkey16 parked in d_out's ctx region (33.5 MB of 64 MB); dead before ctx GEMM writes.
  _Float16* pkey16 = (_Float16*)d_out;            // [B*P, H] f16

  // workspace (71.3 MB peak; aliases are ordered dead-before-write):
  char* wsb = (char*)d_ws;
  _Float16* qkey16   = (_Float16*)(wsb);                        // [B*Q, H]  16.78 MB
  _Float16* k16      = (_Float16*)(wsb + 16777216);             // [B*P, H]  33.55 MB
  _Float16* alphas16 = k16;                                     // alias: k16 dead after proj_k
  _Float16* q16      = (_Float16*)(wsb + 16777216 + 33554432);  // [B*Q, H]  16.78 MB
  _Float16* qT16     = q16;                                     // alias: q16 dead after proj_q
  _Float16* Wk16     = (_Float16*)(wsb + 67108864);             // 2.1 MB
  _Float16* Wq16     = (_Float16*)(wsb + 69206016);             // 2.1 MB

  const long long nK = (long long)B * P * H;   // 16.78M
  const long long nQ = (long long)B * Q * H;   // 8.39M
  const long long nW = (long long)H * H;       // 1.05M

  // 1. converts
  f32_to_f16_kernel<<<(int)(nK / 1024), 256, 0, stream>>>(k, k16, nK);
  f32_to_f16_kernel<<<(int)(nQ / 1024), 256, 0, stream>>>(q, q16, nQ);
  f32_to_f16_kernel<<<(int)(nW / 1024), 256, 0, stream>>>(Wk, Wk16, nW);
  f32_to_f16_kernel<<<(int)(nW / 1024), 256, 0, stream>>>(Wq, Wq16, nW);

  // 2. pkey16 = relu(k16 @ Wk16^T)  [16384 x 1024]
  gemm_nt_f16<<<dim3(H / 128, (B * P) / 128, 1), 256, 0, stream>>>(
      k16, Wk16, nullptr, pkey16, B * P, H, H, 0LL, 0LL, 0LL, 1);
  // 3. qkey16 = relu(q16 @ Wq16^T)  [8192 x 1024]
  gemm_nt_f16<<<dim3(H / 128, (B * Q) / 128, 1), 256, 0, stream>>>(
      q16, Wq16, nullptr, qkey16, B * Q, H, H, 0LL, 0LL, 0LL, 1);
  // 4. scores = pkey16 @ qkey16^T (batched) -> alphas slice fp32
  gemm_nt_f16<<<dim3(Q / 128, P / 128, B), 256, 0, stream>>>(
      pkey16, qkey16, alphas, nullptr, P, Q, H,
      (long long)P * H, (long long)Q * H, (long long)P * Q, 0);
  // 5. qT16 = q^T fp16 (overwrites q16 — q16 dead after step 3)
  transpose_f16_kernel<<<dim3(Q / 64, H / 64, B), 256, 0, stream>>>(q, qT16, Q, H);
  // 6. softmax in place + fp16 copy (alphas16 overwrites k16 — dead after step 2)
  softmax_rows_kernel<<<B * P, 256, 0, stream>>>(alphas, alphas16, qmask, Q, P);
  // 7. ctx = alphas16 @ qT16^T (batched NT) -> d_out base (overwrites pkey16)
  gemm_nt_f16<<<dim3(H / 128, P / 128, B), 256, 0, stream>>>(
      alphas16, qT16, ctx, nullptr, P, H, Q,
      (long long)P * Q, (long long)H * Q, (long long)P * H, 0);
}

// Round 3
// 434.088 us; speedup vs baseline: 3.9321x; 1.0778x over previous
//
#include <hip/hip_runtime.h>
#include <hip/hip_bf16.h>
#include <math.h>

// B=8, P=2048, Q=1024, H=1024
// 1. convert k,q,Wk,Wq fp32 -> fp16 (single fused launch)
// 2. pkey16 = relu(k @ Wk^T)   MFMA f16 (parked in d_out ctx region)
// 3. qkey16 = relu(q @ Wq^T)   MFMA f16
// 4. scores = pkey @ qkey^T    MFMA f16, fp32 -> alphas slice of d_out
// 5. qT16 = transpose(q) fp16
// 6. softmax rows in place + fp16 alphas copy
// 7. ctx = alphas16 @ qT16^T   MFMA f16, fp32 -> d_out base
//
// GEMM: 128x64 tile, BK=32, 256 thr (4 waves, 2x2 grid of 64x32 wave tiles).
// acc = 8 v4f (32 AGPR) -> ~100 combined regs -> 4-5 blocks/CU (vs 3 at R2's
// 128x128 / 132 regs). 1D grid decoded M-fastest so consecutive blocks share
// the B tile (L2/L3 reuse across XCD round-robin).

typedef _Float16 v8h __attribute__((ext_vector_type(8)));
typedef _Float16 v4h __attribute__((ext_vector_type(4)));
typedef float v4f __attribute__((ext_vector_type(4)));

#define AS1C(p) ((const __attribute__((address_space(1))) void*)(p))
#define AS3(p)  ((__attribute__((address_space(3))) void*)(p))

// ---------------------------------------------------------------------------
// NT MFMA GEMM: C[m,n] = sum_k A[m,k]*B[n,k], A:[M,K] B:[N,K] row-major f16.
__global__ __launch_bounds__(256, 4) void gemm_nt_f16(
    const _Float16* __restrict__ A, const _Float16* __restrict__ B,
    float* __restrict__ Cf, _Float16* __restrict__ Ch,
    int N, int K, int Mtiles, int Ntiles,
    long long sA, long long sB, long long sC, int relu)
{
  __shared__ _Float16 As[128 * 32];   // 8 KB
  __shared__ _Float16 Bs[64 * 32];    // 4 KB

  // M-fastest decode: consecutive blocks share the B (N) tile.
  const int bid = blockIdx.x;
  const int mt  = bid % Mtiles;
  const int nt  = (bid / Mtiles) % Ntiles;
  const int bz  = bid / (Mtiles * Ntiles);

  A += (long long)bz * sA;
  B += (long long)bz * sB;

  const int m0 = mt * 128;
  const int n0 = nt * 64;
  const int t  = threadIdx.x;
  const int l  = t & 63;
  const int w  = t >> 6;
  const int wm = (w >> 1) * 64;   // wave m offset (0 or 64)
  const int wn = (w & 1) * 32;    // wave n offset (0 or 32)
  const int fr = l & 15;
  const int fq = l >> 4;

  const int srow = t >> 2;          // 0..63
  const int scol = (t & 3) << 3;    // 0,8,16,24

  v4f acc[4][2];
#pragma unroll
  for (int i = 0; i < 4; ++i)
#pragma unroll
    for (int j = 0; j < 2; ++j)
      acc[i][j] = (v4f){0.f, 0.f, 0.f, 0.f};

  const _Float16* Ap = A + (long long)(m0 + srow) * K + scol;
  const _Float16* Bp = B + (long long)(n0 + srow) * K + scol;

  for (int k0 = 0; k0 < K; k0 += 32) {
    __builtin_amdgcn_global_load_lds(AS1C(Ap + k0),          AS3(As + t * 8),        16, 0, 0);
    __builtin_amdgcn_global_load_lds(AS1C(Ap + 64 * K + k0), AS3(As + 2048 + t * 8), 16, 0, 0);
    __builtin_amdgcn_global_load_lds(AS1C(Bp + k0),          AS3(Bs + t * 8),        16, 0, 0);
    __syncthreads();

    v8h a[4], b[2];
#pragma unroll
    for (int i = 0; i < 4; ++i)
      a[i] = *(const v8h*)&As[(wm + i * 16 + fr) * 32 + fq * 8];
#pragma unroll
    for (int j = 0; j < 2; ++j)
      b[j] = *(const v8h*)&Bs[(wn + j * 16 + fr) * 32 + fq * 8];

#pragma unroll
    for (int i = 0; i < 4; ++i)
#pragma unroll
      for (int j = 0; j < 2; ++j)
        acc[i][j] = __builtin_amdgcn_mfma_f32_16x16x32_f16(a[i], b[j], acc[i][j], 0, 0, 0);

    __syncthreads();
  }

  float* Cfb = Cf ? Cf + (long long)bz * sC : nullptr;
  _Float16* Chb = Ch ? Ch + (long long)bz * sC : nullptr;
#pragma unroll
  for (int i = 0; i < 4; ++i) {
#pragma unroll
    for (int j = 0; j < 2; ++j) {
#pragma unroll
      for (int r = 0; r < 4; ++r) {
        const int row = m0 + wm + i * 16 + fq * 4 + r;
        const int col = n0 + wn + j * 16 + fr;
        float v = acc[i][j][r];
        if (relu) v = fmaxf(v, 0.f);
        if (Cfb) Cfb[(long long)row * N + col] = v;
        if (Chb) Chb[(long long)row * N + col] = (_Float16)v;
      }
    }
  }
}

// ---------------------------------------------------------------------------
// Fused fp32->fp16 conversion of all four inputs in one launch.
// Each block handles 1024 elements of one of the arrays.
__global__ __launch_bounds__(256) void convert_all_kernel(
    const float* __restrict__ s0, _Float16* __restrict__ d0, int b0,  // k
    const float* __restrict__ s1, _Float16* __restrict__ d1, int b1,  // q
    const float* __restrict__ s2, _Float16* __restrict__ d2, int b2,  // Wk
    const float* __restrict__ s3, _Float16* __restrict__ d3)          // Wq
{
  int blk = blockIdx.x;
  const float* src;
  _Float16* dst;
  if (blk < b0)           { src = s0; dst = d0; }
  else if (blk < b0 + b1) { src = s1; dst = d1; blk -= b0; }
  else if (blk < b0 + b1 + b2) { src = s2; dst = d2; blk -= b0 + b1; }
  else                    { src = s3; dst = d3; blk -= b0 + b1 + b2; }
  const long long i = ((long long)blk * 256 + threadIdx.x) * 4;
  const float4 v = *(const float4*)(src + i);
  v4h o = {(_Float16)v.x, (_Float16)v.y, (_Float16)v.z, (_Float16)v.w};
  *(v4h*)(dst + i) = o;
}

// q [B,Q,H] fp32 -> qT [B,H,Q] fp16, 64x64 tiles
__global__ __launch_bounds__(256) void transpose_f16_kernel(
    const float* __restrict__ q, _Float16* __restrict__ qT, int Q, int H)
{
  __shared__ float tile[64][65];
  const float* qb = q + (long long)blockIdx.z * Q * H;
  _Float16* qTb = qT + (long long)blockIdx.z * H * Q;
  const int q0 = blockIdx.x * 64, h0 = blockIdx.y * 64;
  const int t = threadIdx.x;
  const int tr = t >> 4, tc = (t & 15) << 2;
#pragma unroll
  for (int i = 0; i < 4; ++i) {
    const float4 v = *(const float4*)(qb + (long long)(q0 + tr + i * 16) * H + h0 + tc);
    tile[tr + i * 16][tc + 0] = v.x;
    tile[tr + i * 16][tc + 1] = v.y;
    tile[tr + i * 16][tc + 2] = v.z;
    tile[tr + i * 16][tc + 3] = v.w;
  }
  __syncthreads();
#pragma unroll
  for (int i = 0; i < 4; ++i) {
    const int hl = tr + i * 16;
    const int ql = tc;
    v4h o = {(_Float16)tile[ql + 0][hl], (_Float16)tile[ql + 1][hl],
             (_Float16)tile[ql + 2][hl], (_Float16)tile[ql + 3][hl]};
    *(v4h*)(qTb + (long long)(h0 + hl) * Q + q0 + ql) = o;
  }
}

// softmax rows of S [B*P, Q] fp32 in place; also write fp16 copy
__global__ __launch_bounds__(256) void softmax_rows_kernel(
    float* __restrict__ S, _Float16* __restrict__ S16,
    const unsigned char* __restrict__ qmask, int Q, int P)
{
  const long long row = blockIdx.x;       // b*P + p
  const int b = (int)(row / P);
  float* s = S + row * (long long)Q;
  const unsigned char* msk = qmask + (long long)b * Q;
  const int t = threadIdx.x;
  float4 v = *(const float4*)(s + (t << 2));
  float vals[4] = {v.x, v.y, v.z, v.w};
#pragma unroll
  for (int j = 0; j < 4; ++j)
    if (msk[(t << 2) + j]) vals[j] = -INFINITY;

  __shared__ float red[8];
  const int wid = t >> 6, lid = t & 63;

  float mx = fmaxf(fmaxf(vals[0], vals[1]), fmaxf(vals[2], vals[3]));
#pragma unroll
  for (int o = 32; o > 0; o >>= 1) mx = fmaxf(mx, __shfl_xor(mx, o, 64));
  if (lid == 0) red[wid] = mx;
  __syncthreads();
  mx = fmaxf(fmaxf(red[0], red[1]), fmaxf(red[2], red[3]));

  float e[4];
  float sum = 0.f;
#pragma unroll
  for (int j = 0; j < 4; ++j) { e[j] = __expf(vals[j] - mx); sum += e[j]; }
#pragma unroll
  for (int o = 32; o > 0; o >>= 1) sum += __shfl_xor(sum, o, 64);
  __syncthreads();
  if (lid == 0) red[4 + wid] = sum;
  __syncthreads();
  sum = red[4] + red[5] + red[6] + red[7];
  const float inv = 1.f / sum;

  float4 o;
  o.x = e[0] * inv; o.y = e[1] * inv; o.z = e[2] * inv; o.w = e[3] * inv;
  *(float4*)(s + (t << 2)) = o;
  v4h oh = {(_Float16)o.x, (_Float16)o.y, (_Float16)o.z, (_Float16)o.w};
  *(v4h*)(S16 + row * (long long)Q + (t << 2)) = oh;
}

// ---------------------------------------------------------------------------
extern "C" void kernel_launch(void* const* d_in, const int* in_sizes, int n_in,
                              void* d_out, int out_size, void* d_ws, size_t ws_size,
                              hipStream_t stream)
{
  const int B = 8, P = 2048, Q = 1024, H = 1024;
  const float* k  = (const float*)d_in[0];
  const float* q  = (const float*)d_in[1];
  const unsigned char* qmask = (const unsigned char*)d_in[2];
  const float* Wk = (const float*)d_in[3];
  const float* Wq = (const float*)d_in[4];

  float* ctx    = (float*)d_out;                  // [B,P,H] fp32
  float* alphas = ctx + (size_t)B * P * H;        // [B,P,Q] fp32

  _Float16* pkey16 = (_Float16*)d_out;            // parked in ctx region

  char* wsb = (char*)d_ws;
  _Float16* qkey16   = (_Float16*)(wsb);                        // 16.78 MB
  _Float16* k16      = (_Float16*)(wsb + 16777216);             // 33.55 MB
  _Float16* alphas16 = k16;                                     // k16 dead after proj_k
  _Float16* q16      = (_Float16*)(wsb + 16777216 + 33554432);  // 16.78 MB
  _Float16* qT16     = q16;                                     // q16 dead after proj_q
  _Float16* Wk16     = (_Float16*)(wsb + 67108864);
  _Float16* Wq16     = (_Float16*)(wsb + 69206016);

  const long long nK = (long long)B * P * H;   // 16.78M
  const long long nQ = (long long)B * Q * H;   // 8.39M
  const long long nW = (long long)H * H;       // 1.05M

  // 1. fused converts
  const int bK = (int)(nK / 1024), bQ = (int)(nQ / 1024), bW = (int)(nW / 1024);
  convert_all_kernel<<<bK + bQ + 2 * bW, 256, 0, stream>>>(
      k, k16, bK, q, q16, bQ, Wk, Wk16, bW, Wq, Wq16);

  // 2. pkey16 = relu(k16 @ Wk16^T)  [16384 x 1024], tiles 128x64
  gemm_nt_f16<<<(16384 / 128) * (1024 / 64), 256, 0, stream>>>(
      k16, Wk16, nullptr, pkey16, H, H, 16384 / 128, 1024 / 64, 0LL, 0LL, 0LL, 1);
  // 3. qkey16 = relu(q16 @ Wq16^T)  [8192 x 1024]
  gemm_nt_f16<<<(8192 / 128) * (1024 / 64), 256, 0, stream>>>(
      q16, Wq16, nullptr, qkey16, H, H, 8192 / 128, 1024 / 64, 0LL, 0LL, 0LL, 1);
  // 4. scores = pkey16 @ qkey16^T (batched) -> alphas slice fp32
  gemm_nt_f16<<<(P / 128) * (Q / 64) * B, 256, 0, stream>>>(
      pkey16, qkey16, alphas, nullptr, Q, H, P / 128, Q / 64,
      (long long)P * H, (long long)Q * H, (long long)P * Q, 0);
  // 5. qT16 = q^T fp16 (overwrites q16)
  transpose_f16_kernel<<<dim3(Q / 64, H / 64, B), 256, 0, stream>>>(q, qT16, Q, H);
  // 6. softmax in place + fp16 copy (overwrites k16)
  softmax_rows_kernel<<<B * P, 256, 0, stream>>>(alphas, alphas16, qmask, Q, P);
  // 7. ctx = alphas16 @ qT16^T (batched NT) -> d_out base
  gemm_nt_f16<<<(P / 128) * (H / 64) * B, 256, 0, stream>>>(
      alphas16, qT16, ctx, nullptr, H, Q, P / 128, H / 64,
      (long long)P * Q, (long long)H * Q, (long long)P * H, 0);
}